// Round 7
// baseline (154.431 us; speedup 1.0000x reference)
//
#include <hip/hip_runtime.h>

#define TPB 256

typedef float f32x4 __attribute__((ext_vector_type(4)));

// Kernel 1: per-block expert histogram. blockHist[b*E + e] = count of expert e in block b's chunk.
__global__ void k_hist(const int* __restrict__ eidx, int* __restrict__ blockHist,
                       int NK, int E) {
    __shared__ int hist[256];
    int tid = threadIdx.x;
    for (int e = tid; e < E; e += TPB) hist[e] = 0;
    __syncthreads();
    int j = blockIdx.x * TPB + tid;
    if (j < NK) atomicAdd(&hist[eidx[j]], 1);
    __syncthreads();
    for (int e = tid; e < E; e += TPB)
        blockHist[(size_t)blockIdx.x * E + e] = hist[e];
}

// Kernel 2 (single block, 1024 threads): one flat expert-major scan.
// Thread t = (e = t/CH, chunk c = t%CH); chunk-sum over its blocks, Hillis-Steele
// inclusive scan over all E*CH chunk-sums (expert-major order == stable sort order),
// write back blockHist as GLOBAL flat exclusive prefixes (absorbs cross-expert
// offsets), emit inclusive per-expert cumsum as float.
__global__ void k_scan_all(int* __restrict__ blockHist, float* __restrict__ cumsum_out,
                           int numBlocks, int E, int CH) {
    __shared__ int s[1024];
    int t = threadIdx.x;
    int nT = E * CH;                       // <= 1024
    int e = t / CH, c = t % CH;
    int per = (numBlocks + CH - 1) / CH;
    int b0 = c * per;
    int b1 = b0 + per; if (b1 > numBlocks) b1 = numBlocks;
    int sum = 0;
    if (t < nT)
        for (int b = b0; b < b1; ++b) sum += blockHist[(size_t)b * E + e];
    s[t] = (t < nT) ? sum : 0;
    __syncthreads();
    for (int off = 1; off < 1024; off <<= 1) {
        int v = (t >= off) ? s[t - off] : 0;
        __syncthreads();
        s[t] += v;
        __syncthreads();
    }
    if (t < nT) {
        int run = s[t] - sum;              // flat exclusive prefix of my chunk
        for (int b = b0; b < b1; ++b) {
            size_t idx = (size_t)b * E + e;
            int v = blockHist[idx];
            blockHist[idx] = run;
            run += v;
        }
        if (c == CH - 1) cumsum_out[e] = (float)s[t];
    }
}

// Kernel 3: fused position + scatter. One block = TPB flat slots = TPB/K tokens.
// Phase 1: stable pos via ballot match-any (rank in wave) + per-wave expert hist
//          scanned across the block's 4 waves. pos = flatBase[b][e] + wbase + rank.
// Phase 2: read each of the block's tokens' x row once (sequential), NT-scatter to
//          its K destination rows.
__global__ void __launch_bounds__(TPB) k_pos_scatter(
        const int* __restrict__ eidx, const float* __restrict__ scale,
        const int* __restrict__ blockHist, const float* __restrict__ x,
        float* __restrict__ row_idx_out, float* __restrict__ scale_out,
        float* __restrict__ out_x, int NK, int E, int K, int H) {
    __shared__ int pos_sh[TPB];
    __shared__ int whist[4 * 256];
    __shared__ int wbase[4 * 256];
    int tid  = threadIdx.x;
    int j    = blockIdx.x * TPB + tid;
    int wv   = tid >> 6;
    int lane = tid & 63;

    for (int i = tid; i < 4 * E; i += TPB) whist[i] = 0;
    __syncthreads();

    bool valid = (j < NK);
    int e = valid ? eidx[j] : 0;

    // match-any over the wave: lanes with equal e (E <= 256 -> 8 bits)
    unsigned long long mask = __ballot(valid);
    #pragma unroll
    for (int b = 0; b < 8; ++b) {
        unsigned long long bal = __ballot((e >> b) & 1);
        mask &= ((e >> b) & 1) ? bal : ~bal;
    }
    unsigned long long lt = (1ULL << lane) - 1ULL;
    int rank_in_wave = (int)__popcll(mask & lt);
    bool leader = valid && ((mask & lt) == 0);
    if (leader) whist[wv * E + e] = (int)__popcll(mask);
    __syncthreads();

    // scan the 4 wave-hists per expert
    for (int ee = tid; ee < E; ee += TPB) {
        int base = 0;
        #pragma unroll
        for (int w = 0; w < 4; ++w) {
            wbase[w * E + ee] = base;
            base += whist[w * E + ee];
        }
    }
    __syncthreads();

    if (valid) {
        int pos = blockHist[(size_t)blockIdx.x * E + e] + wbase[wv * E + e] + rank_in_wave;
        row_idx_out[j] = (float)pos;
        scale_out[pos] = scale[j / K];
        pos_sh[tid] = pos;
    }
    __syncthreads();

    // Phase 2: scatter this block's tokens
    int tpb_tok = TPB / K;                    // tokens per block
    int tok0 = blockIdx.x * tpb_tok;
    int n4 = H >> 2;
    for (int tl = 0; tl < tpb_tok; ++tl) {
        int tok = tok0 + tl;
        if ((size_t)tok * K >= (size_t)NK) break;
        const f32x4* xs = (const f32x4*)(x + (size_t)tok * H);
        if (K == 8) {
            int p0 = pos_sh[tl * 8 + 0], p1 = pos_sh[tl * 8 + 1];
            int p2 = pos_sh[tl * 8 + 2], p3 = pos_sh[tl * 8 + 3];
            int p4 = pos_sh[tl * 8 + 4], p5 = pos_sh[tl * 8 + 5];
            int p6 = pos_sh[tl * 8 + 6], p7 = pos_sh[tl * 8 + 7];
            for (int t = tid; t < n4; t += TPB) {
                f32x4 v = xs[t];
                __builtin_nontemporal_store(v, (f32x4*)(out_x + (size_t)p0 * H) + t);
                __builtin_nontemporal_store(v, (f32x4*)(out_x + (size_t)p1 * H) + t);
                __builtin_nontemporal_store(v, (f32x4*)(out_x + (size_t)p2 * H) + t);
                __builtin_nontemporal_store(v, (f32x4*)(out_x + (size_t)p3 * H) + t);
                __builtin_nontemporal_store(v, (f32x4*)(out_x + (size_t)p4 * H) + t);
                __builtin_nontemporal_store(v, (f32x4*)(out_x + (size_t)p5 * H) + t);
                __builtin_nontemporal_store(v, (f32x4*)(out_x + (size_t)p6 * H) + t);
                __builtin_nontemporal_store(v, (f32x4*)(out_x + (size_t)p7 * H) + t);
            }
        } else {
            for (int t = tid; t < n4; t += TPB) {
                f32x4 v = xs[t];
                for (int k = 0; k < K; ++k) {
                    f32x4* od = (f32x4*)(out_x + (size_t)pos_sh[tl * K + k] * H);
                    __builtin_nontemporal_store(v, od + t);
                }
            }
        }
    }
}

extern "C" void kernel_launch(void* const* d_in, const int* in_sizes, int n_in,
                              void* d_out, int out_size, void* d_ws, size_t ws_size,
                              hipStream_t stream) {
    const float* x     = (const float*)d_in[0];
    const int*   eidx  = (const int*)d_in[1];
    const float* scale = (const float*)d_in[2];

    const int N  = in_sizes[2];            // scale has N elements
    const int H  = in_sizes[0] / N;        // 1024
    const int K  = in_sizes[1] / N;        // 8
    const int NK = N * K;                  // 131072
    const int E  = out_size - (int)((long long)NK * H) - 2 * NK;   // 64

    const int numBlocks = (NK + TPB - 1) / TPB;  // 512

    // d_out layout (all float)
    float* out_x     = (float*)d_out;
    float* out_rowix = out_x + (size_t)NK * H;
    float* out_cum   = out_rowix + NK;
    float* out_scale = out_cum + E;

    // d_ws: blockHist only
    int* blockHist = (int*)d_ws;                 // numBlocks * E

    int CH = 1024 / E; if (CH < 1) CH = 1;       // chunks per expert, E*CH <= 1024

    k_hist<<<numBlocks, TPB, 0, stream>>>(eidx, blockHist, NK, E);
    k_scan_all<<<1, 1024, 0, stream>>>(blockHist, out_cum, numBlocks, E, CH);
    k_pos_scatter<<<numBlocks, TPB, 0, stream>>>(eidx, scale, blockHist, x,
                                                 out_rowix, out_scale, out_x,
                                                 NK, E, K, H);
}